// Round 3
// baseline (211.213 us; speedup 1.0000x reference)
//
#include <hip/hip_runtime.h>
#include <hip/hip_bf16.h>

// Problem constants (f32 in / f32 out — established R1/R2).
constexpr int B_ = 2, S_ = 2048, D_ = 1024, H_ = 16, KVH_ = 4, HD_ = 64;

typedef __attribute__((ext_vector_type(8))) short short8;
typedef __attribute__((ext_vector_type(4))) float f32x4;
typedef __attribute__((ext_vector_type(16))) float f32x16;

// f32 -> bf16 bits, round-to-nearest-even (finite inputs).
__device__ inline short f2b(float x) {
  unsigned u = __float_as_uint(x);
  return (short)((u + 0x7fffu + ((u >> 16) & 1u)) >> 16);
}
// pack two f32 -> (bf16,bf16) u32, lo in low half (v_cvt_pk_bf16_f32).
__device__ inline unsigned pkbf2(float lo, float hi) {
  __hip_bfloat162 h = __float22bfloat162_rn(float2{lo, hi});
  return *(unsigned*)&h;
}

// Async global->LDS, 16B per lane. LDS dest = wave-uniform base + lane*16.
__device__ inline void async16(void* lds, const void* g) {
  __builtin_amdgcn_global_load_lds(
      (const __attribute__((address_space(1))) unsigned int*)g,
      (__attribute__((address_space(3))) unsigned int*)lds, 16, 0, 0);
}

// Merged prepass: blocks [0,4096) cast x f32->bf16; [4096,5120) transpose
// weights (z: 0=wq, 1=wo, 2=wk, 3=wv; W [1024][N] f32 -> bf16 [N][1024]).
__global__ __launch_bounds__(256) void prep_kernel(
    const float* __restrict__ x, short* __restrict__ xb,
    const float* __restrict__ wq, const float* __restrict__ wk,
    const float* __restrict__ wv, const float* __restrict__ wo,
    short* __restrict__ wt, short* __restrict__ wot) {
  __shared__ short ts[64][66];
  const int tid = threadIdx.x;
  if (blockIdx.x < 4096) {
    const int idx = (blockIdx.x * 256 + tid) * 4;
    float4 v = *(const float4*)(x + idx);
    short4 o;
    o.x = f2b(v.x); o.y = f2b(v.y); o.z = f2b(v.z); o.w = f2b(v.w);
    *(short4*)(xb + idx) = o;
    return;
  }
  const int bid = blockIdx.x - 4096;
  const int z = bid >> 8, bi = (bid >> 4) & 15, bj = bid & 15;
  const float* W;
  short* dst;
  int N;
  if (z == 0)      { W = wq; dst = wt;                       N = 1024; }
  else if (z == 1) { W = wo; dst = wot;                      N = 1024; }
  else if (z == 2) { W = wk; dst = wt + (size_t)1024 * 1024; N = 256; }
  else             { W = wv; dst = wt + (size_t)1280 * 1024; N = 256; }
  if (bj * 64 >= N) return;
#pragma unroll
  for (int i = 0; i < 16; ++i) {
    int idx = tid + i * 256;
    int r = idx >> 6, c = idx & 63;
    ts[r][c] = f2b(W[(size_t)(bi * 64 + r) * N + bj * 64 + c]);
  }
  __syncthreads();
#pragma unroll
  for (int i = 0; i < 16; ++i) {
    int idx = tid + i * 256;
    int cc = idx >> 6, rr = idx & 63;
    dst[(size_t)(bj * 64 + cc) * 1024 + bi * 64 + rr] = ts[rr][cc];
  }
}

// Double-buffered single-barrier MFMA GEMM core (issue-after-barrier): one
// __syncthreads per K-iter; loads for iter k+1 in flight during compute of
// iter k. 128x128 tile, BK=32.
struct GemmLdsDb {
  short As[2][128][32];
  short Bs[2][128][32];
};

__device__ inline void gemm_core_db(GemmLdsDb& lds, const short* __restrict__ A,
                                    const short* __restrict__ Bt, int K,
                                    int row0, int col0, int tid,
                                    f32x4 (&acc)[4][4]) {
  const int w = tid >> 6, lane = tid & 63;
  const int grp = lane >> 4, li = lane & 15;
  const int wr = w & 1, wc = w >> 1;
  const int lr = lane >> 2, ls = (lane & 3) * 8;
#pragma unroll
  for (int mt = 0; mt < 4; ++mt)
#pragma unroll
    for (int nt = 0; nt < 4; ++nt) acc[mt][nt] = (f32x4){0.f, 0.f, 0.f, 0.f};

  auto issue = [&](int bi, int k0) {
#pragma unroll
    for (int i = 0; i < 2; ++i) {
      const int r = i * 64 + w * 16;
      async16(&lds.As[bi][r][0], A + (size_t)(row0 + r + lr) * K + k0 + ls);
      async16(&lds.Bs[bi][r][0], Bt + (size_t)(col0 + r + lr) * K + k0 + ls);
    }
  };

  issue(0, 0);
  const int nk = K >> 5;
  for (int kk = 0; kk < nk; ++kk) {
    const int cur = kk & 1;
    __syncthreads();  // drains only the loads for buffer `cur`
    if (kk + 1 < nk) issue(cur ^ 1, (kk + 1) << 5);

    short8 af[4], bf[4];
#pragma unroll
    for (int mt = 0; mt < 4; ++mt)
      af[mt] = *(const short8*)&lds.As[cur][wr * 64 + mt * 16 + li][grp * 8];
#pragma unroll
    for (int nt = 0; nt < 4; ++nt)
      bf[nt] = *(const short8*)&lds.Bs[cur][wc * 64 + nt * 16 + li][grp * 8];
#pragma unroll
    for (int mt = 0; mt < 4; ++mt)
#pragma unroll
      for (int nt = 0; nt < 4; ++nt)
        acc[mt][nt] = __builtin_amdgcn_mfma_f32_16x16x32_bf16(
            af[mt], bf[nt], acc[mt][nt], 0, 0, 0);
  }
}

// Q scale: 1/sqrt(HD) * log2(e) — fattn uses exp2.
#define QSCALE 0.1803368801111f

// Fused QKV projection over concatenated B^T (N=1536).
__global__ __launch_bounds__(256) void gemm_qkv(
    const short* __restrict__ A, const short* __restrict__ Bt,
    const float* __restrict__ cs, const float* __restrict__ sn,
    short* __restrict__ qb, float* __restrict__ koutp, short* __restrict__ kb,
    float* __restrict__ voutp, short* __restrict__ vbT) {
  __shared__ GemmLdsDb lds;
  const int tid = threadIdx.x;
  const int w = tid >> 6, lane = tid & 63;
  const int grp = lane >> 4, li = lane & 15;
  const int wr = w & 1, wc = w >> 1;
  const int row0 = blockIdx.y * 128, col0 = blockIdx.x * 128;
  f32x4 acc[4][4];
  gemm_core_db(lds, A, Bt, D_, row0, col0, tid, acc);

  if (col0 < 1024) {  // Q: RoPE + QSCALE
#pragma unroll
    for (int mt = 0; mt < 4; ++mt)
#pragma unroll
      for (int r = 0; r < 4; ++r) {
        const int row = row0 + wr * 64 + mt * 16 + grp * 4 + r;
        const int spos = row & (S_ - 1);
#pragma unroll
        for (int nt = 0; nt < 2; ++nt) {
          const int col = col0 + wc * 64 + nt * 16 + li;
          const int d = col & 63;
          const float c = cs[spos * 32 + d];
          const float s = sn[spos * 32 + d];
          const float x0 = acc[mt][nt][r], x1 = acc[mt][nt + 2][r];
          qb[(size_t)row * 1024 + col] = f2b((x0 * c - x1 * s) * QSCALE);
          qb[(size_t)row * 1024 + col + 32] = f2b((x1 * c + x0 * s) * QSCALE);
        }
      }
  } else if (col0 < 1280) {  // K: RoPE, dual write
#pragma unroll
    for (int mt = 0; mt < 4; ++mt)
#pragma unroll
      for (int r = 0; r < 4; ++r) {
        const int row = row0 + wr * 64 + mt * 16 + grp * 4 + r;
        const int spos = row & (S_ - 1);
#pragma unroll
        for (int nt = 0; nt < 2; ++nt) {
          const int kcol = col0 + wc * 64 + nt * 16 + li - 1024;
          const int d = kcol & 63;
          const float c = cs[spos * 32 + d];
          const float s = sn[spos * 32 + d];
          const float x0 = acc[mt][nt][r], x1 = acc[mt][nt + 2][r];
          const float k0v = x0 * c - x1 * s;
          const float k1v = x1 * c + x0 * s;
          koutp[(size_t)row * 256 + kcol] = k0v;
          koutp[(size_t)row * 256 + kcol + 32] = k1v;
          kb[(size_t)row * 256 + kcol] = f2b(k0v);
          kb[(size_t)row * 256 + kcol + 32] = f2b(k1v);
        }
      }
  } else {  // V: f32 natural + bf16 transposed scatter
#pragma unroll
    for (int mt = 0; mt < 4; ++mt)
#pragma unroll
      for (int nt = 0; nt < 4; ++nt) {
        const int vcol = col0 + wc * 64 + nt * 16 + li - 1280;
        const int row_base = row0 + wr * 64 + mt * 16 + grp * 4;
        short4 pk;
        float vv[4];
#pragma unroll
        for (int r = 0; r < 4; ++r) vv[r] = acc[mt][nt][r];
        pk.x = f2b(vv[0]); pk.y = f2b(vv[1]);
        pk.z = f2b(vv[2]); pk.w = f2b(vv[3]);
#pragma unroll
        for (int r = 0; r < 4; ++r)
          voutp[(size_t)(row_base + r) * 256 + vcol] = vv[r];
        const int b = row_base >> 11, s0 = row_base & (S_ - 1);
        *(short4*)&vbT[((size_t)(b * 256 + vcol)) * S_ + s0] = pk;
      }
  }
}

// Flash attention v7: barrier-free + register software pipeline.
// R2 post-mortem: v6 exposed ~200-400cyc L2 latency on every K fragment
// load (MfmaUtil 9%, VALUBusy 26% -> 65% stall). v7 hides it:
//  - K(t+2) prefetched into a ping-pong register pair (kA/kB) while tile t
//    computes -> QK MFMAs start on resident registers.
//  - V(t) loads all issue at body entry; first use is after QK+softmax
//    (~400cyc of MFMA/exp work) -> covered in-iteration.
//  - Hand 2x-unrolled loop, statically-indexed buffers (no scratch).
__global__ __launch_bounds__(128) void fattn_kernel(
    const short* __restrict__ qb, const short* __restrict__ kb,
    const short* __restrict__ vbT, short* __restrict__ o) {
  __shared__ float scr[64 * 33 + 32];  // [d][q] pad-33 transpose + l tail

  const int tid = threadIdx.x;
  const int par = tid >> 6, lane = tid & 63;
  const int n32 = lane & 31, kg = lane >> 5;

  // Descending work order: big blocks dispatch first.
  const int qt = 63 - (blockIdx.x >> 5);  // 32-query tile index [0,64)
  const int bh = blockIdx.x & 31;
  const int b = bh >> 4, h = bh & 15, kh = h >> 2;  // GQA n_rep=4
  const int qq = qt >> 1, st = qt & 1;  // diag 64-key tile / subtile
  const int nt = qq + 1;                // # key tiles of 64

  // Q fragment: rows qt*32+n32, dims kg*8 + ks*16 + e.
  const short* qp =
      qb + ((size_t)(b * S_ + qt * 32 + n32)) * 1024 + h * 64 + kg * 8;
  short8 qa[4];
#pragma unroll
  for (int ks = 0; ks < 4; ++ks) qa[ks] = *(const short8*)(qp + ks * 16);

  // Per-lane K base: key row n32, dim chunk kg*8 (stride 512B across keys).
  const short* kl = kb + ((size_t)(b * S_) + n32) * 256 + kh * 64 + kg * 8;
  // Per-lane V bases: d rows n32 and 32+n32 in transposed V (stride S).
  const short* vl0 = vbT + ((size_t)(b * 256 + kh * 64 + n32)) * S_ + kg * 8;
  const short* vl1 = vl0 + (size_t)32 * S_;

  f32x16 zero16;
#pragma unroll
  for (int i = 0; i < 16; ++i) zero16[i] = 0.f;
  f32x16 Oa0 = zero16, Oa1 = zero16;
  float lreg = 0.f;

  // K fragment loader: full 64-key tile t (both 32-key subtiles).
  auto loadK = [&](int t, short8 (&kr)[8]) {
    const short* kt = kl + (size_t)t * (64 * 256);
#pragma unroll
    for (int i = 0; i < 4; ++i) {
      kr[i] = *(const short8*)(kt + i * 16);
      kr[i + 4] = *(const short8*)(kt + 32 * 256 + i * 16);
    }
  };

  // Full tile compute from resident K registers.
  auto body = [&](int t, const short8 (&kr)[8]) {
    const bool diag = (t == qq);
    const short* vt0 = vl0 + t * 64;
    const short* vt1 = vl1 + t * 64;
    // Early-issue all V fragment loads for this tile.
    short8 vr[8];
#pragma unroll
    for (int kc = 0; kc < 4; ++kc) {
      vr[kc] = *(const short8*)(vt0 + kc * 16);
      vr[kc + 4] = *(const short8*)(vt1 + kc * 16);
    }
    unsigned pk[4][4];
#pragma unroll
    for (int s = 0; s < 2; ++s) {
      if (s == 1 && diag && st == 0) continue;  // fully masked subtile
      f32x16 sv = __builtin_amdgcn_mfma_f32_32x32x16_bf16(kr[s * 4 + 0], qa[0],
                                                          zero16, 0, 0, 0);
      sv = __builtin_amdgcn_mfma_f32_32x32x16_bf16(kr[s * 4 + 1], qa[1], sv, 0,
                                                   0, 0);
      sv = __builtin_amdgcn_mfma_f32_32x32x16_bf16(kr[s * 4 + 2], qa[2], sv, 0,
                                                   0, 0);
      sv = __builtin_amdgcn_mfma_f32_32x32x16_bf16(kr[s * 4 + 3], qa[3], sv, 0,
                                                   0, 0);
      const bool dm = diag && (s == st);  // partial-masked subtile
      float e[16];
#pragma unroll
      for (int rr = 0; rr < 16; ++rr) {
        float v = __builtin_amdgcn_exp2f(sv[rr]);
        if (dm) {
          const int key32 = (rr & 3) + 8 * (rr >> 2) + 4 * kg;
          if (key32 > n32) v = 0.f;
        }
        e[rr] = v;
      }
      pk[2 * s][0] = pkbf2(e[0], e[1]);
      pk[2 * s][1] = pkbf2(e[2], e[3]);
      pk[2 * s][2] = pkbf2(e[4], e[5]);
      pk[2 * s][3] = pkbf2(e[6], e[7]);
      pk[2 * s + 1][0] = pkbf2(e[8], e[9]);
      pk[2 * s + 1][1] = pkbf2(e[10], e[11]);
      pk[2 * s + 1][2] = pkbf2(e[12], e[13]);
      pk[2 * s + 1][3] = pkbf2(e[14], e[15]);
      lreg += (((e[0] + e[1]) + (e[2] + e[3])) +
               ((e[4] + e[5]) + (e[6] + e[7]))) +
              (((e[8] + e[9]) + (e[10] + e[11])) +
               ((e[12] + e[13]) + (e[14] + e[15])));
    }

    auto pv = [&](int kc) {
      // Build B fragment: lanes<32 need {own p01,p23 | other-half p45,p67},
      // lanes>=32 the mirror — one permlane32_swap per reg pair.
      auto r02 =
          __builtin_amdgcn_permlane32_swap(pk[kc][0], pk[kc][2], false, false);
      auto r13 =
          __builtin_amdgcn_permlane32_swap(pk[kc][1], pk[kc][3], false, false);
      union { unsigned u[4]; short8 s8; } f;
      f.u[0] = r02[0]; f.u[1] = r13[0]; f.u[2] = r02[1]; f.u[3] = r13[1];
      Oa0 = __builtin_amdgcn_mfma_f32_32x32x16_bf16(vr[kc], f.s8, Oa0, 0, 0, 0);
      Oa1 = __builtin_amdgcn_mfma_f32_32x32x16_bf16(vr[kc + 4], f.s8, Oa1, 0,
                                                    0, 0);
    };
    if (diag && st == 0) {
      pv(0); pv(1);
    } else {
      pv(0); pv(1); pv(2); pv(3);
    }
  };

  // Software-pipelined main loop: ping-pong K register buffers.
  {
    short8 kA[8], kB[8];
    int t = par;
    if (t < nt) {
      loadK(t, kA);
      while (true) {
        {
          const int tp = (t + 2 < nt) ? t + 2 : t;
          loadK(tp, kB);  // prefetch next tile of this wave's parity
          body(t, kA);
          t += 2;
          if (t >= nt) break;
        }
        {
          const int tp = (t + 2 < nt) ? t + 2 : t;
          loadK(tp, kA);
          body(t, kB);
          t += 2;
          if (t >= nt) break;
        }
      }
    }
  }

  // Combine kg halves of l (same q, disjoint keys).
  lreg += __shfl_xor(lreg, 32);

  // Cross-parity combine + normalize + coalesced write via LDS scratch.
  float* lb = scr + 64 * 33;
  if (par == 1) {
#pragma unroll
    for (int rr = 0; rr < 16; ++rr) {
      const int d0 = (rr & 3) + 8 * (rr >> 2) + 4 * kg;
      scr[d0 * 33 + n32] = Oa0[rr];
      scr[(d0 + 32) * 33 + n32] = Oa1[rr];
    }
    if (kg == 0) lb[n32] = lreg;
  }
  __syncthreads();
  if (par == 0) {
    const float inv = __builtin_amdgcn_rcpf(lreg + lb[n32]);
#pragma unroll
    for (int rr = 0; rr < 16; ++rr) {
      const int d0 = (rr & 3) + 8 * (rr >> 2) + 4 * kg;
      scr[d0 * 33 + n32] = (Oa0[rr] + scr[d0 * 33 + n32]) * inv;
      scr[(d0 + 32) * 33 + n32] = (Oa1[rr] + scr[(d0 + 32) * 33 + n32]) * inv;
    }
  }
  __syncthreads();
  {
    const int q = tid >> 2, seg = (tid & 3) * 16;
    const size_t gb = ((size_t)(b * S_ + qt * 32 + q)) * 1024 + h * 64 + seg;
    short8 t0, t1;
#pragma unroll
    for (int k2 = 0; k2 < 8; ++k2) {
      t0[k2] = f2b(scr[(seg + k2) * 33 + q]);
      t1[k2] = f2b(scr[(seg + 8 + k2) * 33 + q]);
    }
    *(short8*)(o + gb) = t0;
    *(short8*)(o + gb + 8) = t1;
  }
}

// O-projection: 128x128 tiles, dbuf core, f32 output.
__global__ __launch_bounds__(256) void gemm_bt_f32(
    const short* __restrict__ A, const short* __restrict__ Bt,
    float* __restrict__ C, int N, int K) {
  __shared__ GemmLdsDb lds;
  const int tid = threadIdx.x;
  const int w = tid >> 6, lane = tid & 63;
  const int grp = lane >> 4, li = lane & 15;
  const int wr = w & 1, wc = w >> 1;
  const int row0 = blockIdx.y * 128, col0 = blockIdx.x * 128;
  f32x4 acc[4][4];
  gemm_core_db(lds, A, Bt, K, row0, col0, tid, acc);
#pragma unroll
  for (int mt = 0; mt < 4; ++mt)
#pragma unroll
    for (int nt = 0; nt < 4; ++nt)
#pragma unroll
      for (int r = 0; r < 4; ++r)
        C[(size_t)(row0 + wr * 64 + mt * 16 + grp * 4 + r) * N + col0 +
          wc * 64 + nt * 16 + li] = acc[mt][nt][r];
}

extern "C" void kernel_launch(void* const* d_in, const int* in_sizes, int n_in,
                              void* d_out, int out_size, void* d_ws,
                              size_t ws_size, hipStream_t stream) {
  const float* x  = (const float*)d_in[0];
  const float* cs = (const float*)d_in[1];
  const float* sn = (const float*)d_in[2];
  // d_in[3] = mask (causal, analytic)
  const float* wq = (const float*)d_in[4];
  const float* wk = (const float*)d_in[5];
  const float* wv = (const float*)d_in[6];
  const float* wo = (const float*)d_in[7];

  float* outp  = (float*)d_out;
  float* koutp = outp + (size_t)B_ * S_ * H_ * HD_;     // new_k (f32)
  float* voutp = koutp + (size_t)B_ * S_ * KVH_ * HD_;  // new_v (f32)

  char* p = (char*)d_ws;
  short* xb   = (short*)p; p += (size_t)B_ * S_ * D_ * 2;          // 8 MB
  short* qb   = (short*)p; p += (size_t)B_ * S_ * H_ * HD_ * 2;    // 8 MB
  short* kb   = (short*)p; p += (size_t)B_ * S_ * KVH_ * HD_ * 2;  // 2 MB
  short* vbT  = (short*)p; p += (size_t)B_ * S_ * KVH_ * HD_ * 2;  // 2 MB
  short* abuf = (short*)p; p += (size_t)B_ * S_ * H_ * HD_ * 2;    // 8 MB
  short* wt   = (short*)p; p += (size_t)1536 * D_ * 2;             // 3 MB
  short* wot  = (short*)p; p += (size_t)D_ * H_ * HD_ * 2;         // 2 MB

  const int M = B_ * S_;  // 4096

  // Prepass: bf16 cast + all weight transposes (single launch).
  prep_kernel<<<4096 + 1024, 256, 0, stream>>>(x, xb, wq, wk, wv, wo, wt,
                                               wot);

  // Fused QKV projection (MFMA, dbuf) with RoPE / transpose epilogues.
  gemm_qkv<<<dim3(1536 / 128, M / 128), 256, 0, stream>>>(
      xb, wt, cs, sn, qb, koutp, kb, voutp, vbT);

  // Flash attention v7: 2048 blocks, barrier-free, register pipeline.
  fattn_kernel<<<64 * 32, 128, 0, stream>>>(qb, kb, vbT, abuf);

  // Output projection (MFMA, dbuf) -> f32 d_out.
  gemm_bt_f32<<<dim3(1024 / 128, M / 128), 256, 0, stream>>>(abuf, wot, outp,
                                                             1024, 1024);
}

// Round 4
// 171.461 us; speedup vs baseline: 1.2318x; 1.2318x over previous
//
#include <hip/hip_runtime.h>
#include <hip/hip_bf16.h>

// Problem constants (f32 in / f32 out — established R1/R2).
constexpr int B_ = 2, S_ = 2048, D_ = 1024, H_ = 16, KVH_ = 4, HD_ = 64;

typedef __attribute__((ext_vector_type(8))) short short8;
typedef __attribute__((ext_vector_type(4))) float f32x4;
typedef __attribute__((ext_vector_type(16))) float f32x16;

// f32 -> bf16 bits, round-to-nearest-even (finite inputs).
__device__ inline short f2b(float x) {
  unsigned u = __float_as_uint(x);
  return (short)((u + 0x7fffu + ((u >> 16) & 1u)) >> 16);
}
// pack two f32 -> (bf16,bf16) u32, lo in low half (v_cvt_pk_bf16_f32).
__device__ inline unsigned pkbf2(float lo, float hi) {
  __hip_bfloat162 h = __float22bfloat162_rn(float2{lo, hi});
  return *(unsigned*)&h;
}

// Async global->LDS, 16B per lane. LDS dest = wave-uniform base + lane*16.
__device__ inline void async16(void* lds, const void* g) {
  __builtin_amdgcn_global_load_lds(
      (const __attribute__((address_space(1))) unsigned int*)g,
      (__attribute__((address_space(3))) unsigned int*)lds, 16, 0, 0);
}

// Merged prepass: blocks [0,4096) cast x f32->bf16; [4096,5120) transpose
// weights (z: 0=wq, 1=wo, 2=wk, 3=wv; W [1024][N] f32 -> bf16 [N][1024]).
__global__ __launch_bounds__(256) void prep_kernel(
    const float* __restrict__ x, short* __restrict__ xb,
    const float* __restrict__ wq, const float* __restrict__ wk,
    const float* __restrict__ wv, const float* __restrict__ wo,
    short* __restrict__ wt, short* __restrict__ wot) {
  __shared__ short ts[64][66];
  const int tid = threadIdx.x;
  if (blockIdx.x < 4096) {
    const int idx = (blockIdx.x * 256 + tid) * 4;
    float4 v = *(const float4*)(x + idx);
    short4 o;
    o.x = f2b(v.x); o.y = f2b(v.y); o.z = f2b(v.z); o.w = f2b(v.w);
    *(short4*)(xb + idx) = o;
    return;
  }
  const int bid = blockIdx.x - 4096;
  const int z = bid >> 8, bi = (bid >> 4) & 15, bj = bid & 15;
  const float* W;
  short* dst;
  int N;
  if (z == 0)      { W = wq; dst = wt;                       N = 1024; }
  else if (z == 1) { W = wo; dst = wot;                      N = 1024; }
  else if (z == 2) { W = wk; dst = wt + (size_t)1024 * 1024; N = 256; }
  else             { W = wv; dst = wt + (size_t)1280 * 1024; N = 256; }
  if (bj * 64 >= N) return;
#pragma unroll
  for (int i = 0; i < 16; ++i) {
    int idx = tid + i * 256;
    int r = idx >> 6, c = idx & 63;
    ts[r][c] = f2b(W[(size_t)(bi * 64 + r) * N + bj * 64 + c]);
  }
  __syncthreads();
#pragma unroll
  for (int i = 0; i < 16; ++i) {
    int idx = tid + i * 256;
    int cc = idx >> 6, rr = idx & 63;
    dst[(size_t)(bj * 64 + cc) * 1024 + bi * 64 + rr] = ts[rr][cc];
  }
}

// Double-buffered single-barrier MFMA GEMM core (issue-after-barrier): one
// __syncthreads per K-iter; loads for iter k+1 in flight during compute of
// iter k. 128x128 tile, BK=32.
struct GemmLdsDb {
  short As[2][128][32];
  short Bs[2][128][32];
};

__device__ inline void gemm_core_db(GemmLdsDb& lds, const short* __restrict__ A,
                                    const short* __restrict__ Bt, int K,
                                    int row0, int col0, int tid,
                                    f32x4 (&acc)[4][4]) {
  const int w = tid >> 6, lane = tid & 63;
  const int grp = lane >> 4, li = lane & 15;
  const int wr = w & 1, wc = w >> 1;
  const int lr = lane >> 2, ls = (lane & 3) * 8;
#pragma unroll
  for (int mt = 0; mt < 4; ++mt)
#pragma unroll
    for (int nt = 0; nt < 4; ++nt) acc[mt][nt] = (f32x4){0.f, 0.f, 0.f, 0.f};

  auto issue = [&](int bi, int k0) {
#pragma unroll
    for (int i = 0; i < 2; ++i) {
      const int r = i * 64 + w * 16;
      async16(&lds.As[bi][r][0], A + (size_t)(row0 + r + lr) * K + k0 + ls);
      async16(&lds.Bs[bi][r][0], Bt + (size_t)(col0 + r + lr) * K + k0 + ls);
    }
  };

  issue(0, 0);
  const int nk = K >> 5;
  for (int kk = 0; kk < nk; ++kk) {
    const int cur = kk & 1;
    __syncthreads();  // drains only the loads for buffer `cur`
    if (kk + 1 < nk) issue(cur ^ 1, (kk + 1) << 5);

    short8 af[4], bf[4];
#pragma unroll
    for (int mt = 0; mt < 4; ++mt)
      af[mt] = *(const short8*)&lds.As[cur][wr * 64 + mt * 16 + li][grp * 8];
#pragma unroll
    for (int nt = 0; nt < 4; ++nt)
      bf[nt] = *(const short8*)&lds.Bs[cur][wc * 64 + nt * 16 + li][grp * 8];
#pragma unroll
    for (int mt = 0; mt < 4; ++mt)
#pragma unroll
      for (int nt = 0; nt < 4; ++nt)
        acc[mt][nt] = __builtin_amdgcn_mfma_f32_16x16x32_bf16(
            af[mt], bf[nt], acc[mt][nt], 0, 0, 0);
  }
}

// Q scale: 1/sqrt(HD) * log2(e) — fattn uses exp2.
#define QSCALE 0.1803368801111f

// Fused QKV projection over concatenated B^T (N=1536).
// K/V bf16 outputs are written in MFMA-FRAGMENT order (R4):
//  kbF[b][kh][sb32][ks*2+kg][key32][8]  (2048 shorts per 32-key block)
//  vbF[b][kh][t64][dhalf][kc][kg][d32][8] (4096 shorts per 64-key tile)
// so fattn's fragment loads are base + lane*16B contiguous (1KB/wave-load).
__global__ __launch_bounds__(256) void gemm_qkv(
    const short* __restrict__ A, const short* __restrict__ Bt,
    const float* __restrict__ cs, const float* __restrict__ sn,
    short* __restrict__ qb, float* __restrict__ koutp, short* __restrict__ kb,
    float* __restrict__ voutp, short* __restrict__ vbT) {
  __shared__ GemmLdsDb lds;
  const int tid = threadIdx.x;
  const int w = tid >> 6, lane = tid & 63;
  const int grp = lane >> 4, li = lane & 15;
  const int wr = w & 1, wc = w >> 1;
  const int row0 = blockIdx.y * 128, col0 = blockIdx.x * 128;
  f32x4 acc[4][4];
  gemm_core_db(lds, A, Bt, D_, row0, col0, tid, acc);

  if (col0 < 1024) {  // Q: RoPE + QSCALE
#pragma unroll
    for (int mt = 0; mt < 4; ++mt)
#pragma unroll
      for (int r = 0; r < 4; ++r) {
        const int row = row0 + wr * 64 + mt * 16 + grp * 4 + r;
        const int spos = row & (S_ - 1);
#pragma unroll
        for (int nt = 0; nt < 2; ++nt) {
          const int col = col0 + wc * 64 + nt * 16 + li;
          const int d = col & 63;
          const float c = cs[spos * 32 + d];
          const float s = sn[spos * 32 + d];
          const float x0 = acc[mt][nt][r], x1 = acc[mt][nt + 2][r];
          qb[(size_t)row * 1024 + col] = f2b((x0 * c - x1 * s) * QSCALE);
          qb[(size_t)row * 1024 + col + 32] = f2b((x1 * c + x0 * s) * QSCALE);
        }
      }
  } else if (col0 < 1280) {  // K: RoPE, f32 natural + bf16 fragment-packed
#pragma unroll
    for (int mt = 0; mt < 4; ++mt)
#pragma unroll
      for (int r = 0; r < 4; ++r) {
        const int row = row0 + wr * 64 + mt * 16 + grp * 4 + r;
        const int bq = row >> 11, spos = row & (S_ - 1);
        const int sb = spos >> 5, k32 = spos & 31;
#pragma unroll
        for (int nt = 0; nt < 2; ++nt) {
          const int kcol = col0 + wc * 64 + nt * 16 + li - 1024;
          const int khk = kcol >> 6, d = kcol & 63;  // d in [0,32)
          const float c = cs[spos * 32 + d];
          const float s = sn[spos * 32 + d];
          const float x0 = acc[mt][nt][r], x1 = acc[mt][nt + 2][r];
          const float k0v = x0 * c - x1 * s;
          const float k1v = x1 * c + x0 * s;
          koutp[(size_t)row * 256 + kcol] = k0v;
          koutp[(size_t)row * 256 + kcol + 32] = k1v;
          short* kbase =
              kb + (((size_t)(bq * 4 + khk) * 64 + sb) * 2048) + k32 * 8;
          const int d2 = d + 32;
          kbase[((d >> 4) * 2 + ((d >> 3) & 1)) * 256 + (d & 7)] = f2b(k0v);
          kbase[((d2 >> 4) * 2 + ((d2 >> 3) & 1)) * 256 + (d2 & 7)] = f2b(k1v);
        }
      }
  } else {  // V: f32 natural + bf16 fragment-packed
#pragma unroll
    for (int mt = 0; mt < 4; ++mt)
#pragma unroll
      for (int nt = 0; nt < 4; ++nt) {
        const int vcol = col0 + wc * 64 + nt * 16 + li - 1280;
        const int row_base = row0 + wr * 64 + mt * 16 + grp * 4;
        short4 pk;
        float vv[4];
#pragma unroll
        for (int r = 0; r < 4; ++r) vv[r] = acc[mt][nt][r];
        pk.x = f2b(vv[0]); pk.y = f2b(vv[1]);
        pk.z = f2b(vv[2]); pk.w = f2b(vv[3]);
#pragma unroll
        for (int r = 0; r < 4; ++r)
          voutp[(size_t)(row_base + r) * 256 + vcol] = vv[r];
        const int bq = row_base >> 11, s0 = row_base & (S_ - 1);
        const int t = s0 >> 6, k64 = s0 & 63;
        const int kc = k64 >> 4, kg8 = (k64 >> 3) & 1, k8 = k64 & 7;
        const int khv = vcol >> 6, d = vcol & 63;
        short* vb = vbT + (((size_t)(bq * 4 + khv) * 32 + t) * 4096) +
                    (d >> 5) * 2048 + kc * 512 + kg8 * 256 + (d & 31) * 8 + k8;
        *(short4*)vb = pk;
      }
  }
}

// Flash attention v8: barrier-free + register pipeline + COALESCED loads.
// R3 post-mortem: v6/v7 K loads had 512B lane stride, V 4KB stride -> every
// wave-load touched 64 distinct cache lines; ~35M line-requests serialized
// the per-CU memory pipe (~40-60us). Fix: K/V stored fragment-packed by the
// QKV epilogue, so every fragment load here is base + lane*16B (1KB
// contiguous). Also: V(t) loads issue BEFORE K(t+2) prefetch so the PV
// vmcnt wait doesn't drain the prefetch (FIFO order).
__global__ __launch_bounds__(128) void fattn_kernel(
    const short* __restrict__ qb, const short* __restrict__ kb,
    const short* __restrict__ vbT, short* __restrict__ o) {
  __shared__ float scr[64 * 33 + 32];  // [d][q] pad-33 transpose + l tail

  const int tid = threadIdx.x;
  const int par = tid >> 6, lane = tid & 63;
  const int n32 = lane & 31, kg = lane >> 5;

  // Descending work order: big blocks dispatch first.
  const int qt = 63 - (blockIdx.x >> 5);  // 32-query tile index [0,64)
  const int bh = blockIdx.x & 31;
  const int b = bh >> 4, h = bh & 15, kh = h >> 2;  // GQA n_rep=4
  const int qq = qt >> 1, st = qt & 1;  // diag 64-key tile / subtile
  const int nt = qq + 1;                // # key tiles of 64

  // Q fragment: rows qt*32+n32, dims kg*8 + ks*16 + e.
  const short* qp =
      qb + ((size_t)(b * S_ + qt * 32 + n32)) * 1024 + h * 64 + kg * 8;
  short8 qa[4];
#pragma unroll
  for (int ks = 0; ks < 4; ++ks) qa[ks] = *(const short8*)(qp + ks * 16);

  // Fragment-packed K/V bases: per-(b,kh) stride 131072 shorts (256KB).
  const short* kF = kb + ((size_t)(b * 4 + kh) << 17) + lane * 8;
  const short* vF = vbT + ((size_t)(b * 4 + kh) << 17) + lane * 8;

  f32x16 zero16;
#pragma unroll
  for (int i = 0; i < 16; ++i) zero16[i] = 0.f;
  f32x16 Oa0 = zero16, Oa1 = zero16;
  float lreg = 0.f;

  // K fragment loader: full 64-key tile t — 8 contiguous 1KB wave-loads.
  auto loadK = [&](int t, short8 (&kr)[8]) {
    const short* kt = kF + (size_t)t * 4096;
#pragma unroll
    for (int s = 0; s < 2; ++s)
#pragma unroll
      for (int ks = 0; ks < 4; ++ks)
        kr[s * 4 + ks] = *(const short8*)(kt + s * 2048 + ks * 512);
  };

  // Tile body: V loads first, then K(t+2) prefetch, then compute on
  // resident kr registers.
  auto body = [&](int t, const short8 (&kr)[8], short8 (&knx)[8]) {
    const bool diag = (t == qq);
    const short* vt = vF + (size_t)t * 4096;
    short8 vr[8];
#pragma unroll
    for (int kc = 0; kc < 4; ++kc) {
      vr[kc] = *(const short8*)(vt + kc * 512);
      vr[kc + 4] = *(const short8*)(vt + 2048 + kc * 512);
    }
    if (t + 2 < nt) loadK(t + 2, knx);  // wave-uniform branch

    unsigned pk[4][4];
#pragma unroll
    for (int s = 0; s < 2; ++s) {
      if (s == 1 && diag && st == 0) continue;  // fully masked subtile
      f32x16 sv = __builtin_amdgcn_mfma_f32_32x32x16_bf16(kr[s * 4 + 0], qa[0],
                                                          zero16, 0, 0, 0);
      sv = __builtin_amdgcn_mfma_f32_32x32x16_bf16(kr[s * 4 + 1], qa[1], sv, 0,
                                                   0, 0);
      sv = __builtin_amdgcn_mfma_f32_32x32x16_bf16(kr[s * 4 + 2], qa[2], sv, 0,
                                                   0, 0);
      sv = __builtin_amdgcn_mfma_f32_32x32x16_bf16(kr[s * 4 + 3], qa[3], sv, 0,
                                                   0, 0);
      const bool dm = diag && (s == st);  // partial-masked subtile
      float e[16];
#pragma unroll
      for (int rr = 0; rr < 16; ++rr) {
        float v = __builtin_amdgcn_exp2f(sv[rr]);
        if (dm) {
          const int key32 = (rr & 3) + 8 * (rr >> 2) + 4 * kg;
          if (key32 > n32) v = 0.f;
        }
        e[rr] = v;
      }
      pk[2 * s][0] = pkbf2(e[0], e[1]);
      pk[2 * s][1] = pkbf2(e[2], e[3]);
      pk[2 * s][2] = pkbf2(e[4], e[5]);
      pk[2 * s][3] = pkbf2(e[6], e[7]);
      pk[2 * s + 1][0] = pkbf2(e[8], e[9]);
      pk[2 * s + 1][1] = pkbf2(e[10], e[11]);
      pk[2 * s + 1][2] = pkbf2(e[12], e[13]);
      pk[2 * s + 1][3] = pkbf2(e[14], e[15]);
      lreg += (((e[0] + e[1]) + (e[2] + e[3])) +
               ((e[4] + e[5]) + (e[6] + e[7]))) +
              (((e[8] + e[9]) + (e[10] + e[11])) +
               ((e[12] + e[13]) + (e[14] + e[15])));
    }

    auto pv = [&](int kc) {
      // Build B fragment: lanes<32 need {own p01,p23 | other-half p45,p67},
      // lanes>=32 the mirror — one permlane32_swap per reg pair.
      auto r02 =
          __builtin_amdgcn_permlane32_swap(pk[kc][0], pk[kc][2], false, false);
      auto r13 =
          __builtin_amdgcn_permlane32_swap(pk[kc][1], pk[kc][3], false, false);
      union { unsigned u[4]; short8 s8; } f;
      f.u[0] = r02[0]; f.u[1] = r13[0]; f.u[2] = r02[1]; f.u[3] = r13[1];
      Oa0 = __builtin_amdgcn_mfma_f32_32x32x16_bf16(vr[kc], f.s8, Oa0, 0, 0, 0);
      Oa1 = __builtin_amdgcn_mfma_f32_32x32x16_bf16(vr[kc + 4], f.s8, Oa1, 0,
                                                    0, 0);
    };
    if (diag && st == 0) {
      pv(0); pv(1);
    } else {
      pv(0); pv(1); pv(2); pv(3);
    }
  };

  // Software-pipelined main loop: ping-pong K register buffers.
  {
    short8 kA[8], kB[8];
    int t = par;
    if (t < nt) {
      loadK(t, kA);
      for (;;) {
        body(t, kA, kB);
        t += 2;
        if (t >= nt) break;
        body(t, kB, kA);
        t += 2;
        if (t >= nt) break;
      }
    }
  }

  // Combine kg halves of l (same q, disjoint keys).
  lreg += __shfl_xor(lreg, 32);

  // Cross-parity combine + normalize + coalesced write via LDS scratch.
  float* lb = scr + 64 * 33;
  if (par == 1) {
#pragma unroll
    for (int rr = 0; rr < 16; ++rr) {
      const int d0 = (rr & 3) + 8 * (rr >> 2) + 4 * kg;
      scr[d0 * 33 + n32] = Oa0[rr];
      scr[(d0 + 32) * 33 + n32] = Oa1[rr];
    }
    if (kg == 0) lb[n32] = lreg;
  }
  __syncthreads();
  if (par == 0) {
    const float inv = __builtin_amdgcn_rcpf(lreg + lb[n32]);
#pragma unroll
    for (int rr = 0; rr < 16; ++rr) {
      const int d0 = (rr & 3) + 8 * (rr >> 2) + 4 * kg;
      scr[d0 * 33 + n32] = (Oa0[rr] + scr[d0 * 33 + n32]) * inv;
      scr[(d0 + 32) * 33 + n32] = (Oa1[rr] + scr[(d0 + 32) * 33 + n32]) * inv;
    }
  }
  __syncthreads();
  {
    const int q = tid >> 2, seg = (tid & 3) * 16;
    const size_t gb = ((size_t)(b * S_ + qt * 32 + q)) * 1024 + h * 64 + seg;
    short8 t0, t1;
#pragma unroll
    for (int k2 = 0; k2 < 8; ++k2) {
      t0[k2] = f2b(scr[(seg + k2) * 33 + q]);
      t1[k2] = f2b(scr[(seg + 8 + k2) * 33 + q]);
    }
    *(short8*)(o + gb) = t0;
    *(short8*)(o + gb + 8) = t1;
  }
}

// O-projection: 128x128 tiles, dbuf core, f32 output.
__global__ __launch_bounds__(256) void gemm_bt_f32(
    const short* __restrict__ A, const short* __restrict__ Bt,
    float* __restrict__ C, int N, int K) {
  __shared__ GemmLdsDb lds;
  const int tid = threadIdx.x;
  const int w = tid >> 6, lane = tid & 63;
  const int grp = lane >> 4, li = lane & 15;
  const int wr = w & 1, wc = w >> 1;
  const int row0 = blockIdx.y * 128, col0 = blockIdx.x * 128;
  f32x4 acc[4][4];
  gemm_core_db(lds, A, Bt, K, row0, col0, tid, acc);
#pragma unroll
  for (int mt = 0; mt < 4; ++mt)
#pragma unroll
    for (int nt = 0; nt < 4; ++nt)
#pragma unroll
      for (int r = 0; r < 4; ++r)
        C[(size_t)(row0 + wr * 64 + mt * 16 + grp * 4 + r) * N + col0 +
          wc * 64 + nt * 16 + li] = acc[mt][nt][r];
}

extern "C" void kernel_launch(void* const* d_in, const int* in_sizes, int n_in,
                              void* d_out, int out_size, void* d_ws,
                              size_t ws_size, hipStream_t stream) {
  const float* x  = (const float*)d_in[0];
  const float* cs = (const float*)d_in[1];
  const float* sn = (const float*)d_in[2];
  // d_in[3] = mask (causal, analytic)
  const float* wq = (const float*)d_in[4];
  const float* wk = (const float*)d_in[5];
  const float* wv = (const float*)d_in[6];
  const float* wo = (const float*)d_in[7];

  float* outp  = (float*)d_out;
  float* koutp = outp + (size_t)B_ * S_ * H_ * HD_;     // new_k (f32)
  float* voutp = koutp + (size_t)B_ * S_ * KVH_ * HD_;  // new_v (f32)

  char* p = (char*)d_ws;
  short* xb   = (short*)p; p += (size_t)B_ * S_ * D_ * 2;          // 8 MB
  short* qb   = (short*)p; p += (size_t)B_ * S_ * H_ * HD_ * 2;    // 8 MB
  short* kb   = (short*)p; p += (size_t)B_ * S_ * KVH_ * HD_ * 2;  // 2 MB
  short* vbT  = (short*)p; p += (size_t)B_ * S_ * KVH_ * HD_ * 2;  // 2 MB
  short* abuf = (short*)p; p += (size_t)B_ * S_ * H_ * HD_ * 2;    // 8 MB
  short* wt   = (short*)p; p += (size_t)1536 * D_ * 2;             // 3 MB
  short* wot  = (short*)p; p += (size_t)D_ * H_ * HD_ * 2;         // 2 MB

  const int M = B_ * S_;  // 4096

  // Prepass: bf16 cast + all weight transposes (single launch).
  prep_kernel<<<4096 + 1024, 256, 0, stream>>>(x, xb, wq, wk, wv, wo, wt,
                                               wot);

  // Fused QKV projection (MFMA, dbuf) with RoPE / fragment-pack epilogues.
  gemm_qkv<<<dim3(1536 / 128, M / 128), 256, 0, stream>>>(
      xb, wt, cs, sn, qb, koutp, kb, voutp, vbT);

  // Flash attention v8: 2048 blocks, barrier-free, coalesced fragment loads.
  fattn_kernel<<<64 * 32, 128, 0, stream>>>(qb, kb, vbT, abuf);

  // Output projection (MFMA, dbuf) -> f32 d_out.
  gemm_bt_f32<<<dim3(1024 / 128, M / 128), 256, 0, stream>>>(abuf, wot, outp,
                                                             1024, 1024);
}